// Round 5
// baseline (62.313 us; speedup 1.0000x reference)
//
#include <hip/hip_runtime.h>
#include <hip/hip_bf16.h>

#define DDIM   256   // K (feature dim)
#define BROWS  256   // block output rows (4 waves x 64 rows)
#define BCOLS   32   // B tile columns
#define NTILES   8   // B tiles per block -> 256 cols per chunk

typedef __bf16 bf16x8 __attribute__((ext_vector_type(8)));
typedef float  f32x4  __attribute__((ext_vector_type(4)));
typedef int    i32x4  __attribute__((ext_vector_type(4)));

// round-to-nearest-even f32 -> bf16 bits
__device__ __forceinline__ unsigned short f2bf(float f) {
  unsigned int u = __float_as_uint(f);
  return (unsigned short)((u + 0x7fffu + ((u >> 16) & 1u)) >> 16);
}

// ---- prep: one wave per row; writes UNIT-NORM bf16 rows + exact f32 diag ----
__global__ __launch_bounds__(256) void prep_kernel(
    const float* __restrict__ q, const float* __restrict__ r,
    unsigned short* __restrict__ qbf, unsigned short* __restrict__ rbf,
    float* __restrict__ pos, float* __restrict__ row_sum) {
  int lane = threadIdx.x & 63, wave = threadIdx.x >> 6;
  int row = blockIdx.x * 4 + wave;
  size_t base = (size_t)row * DDIM + lane * 4;
  float4 qv = *(const float4*)(q + base);
  float4 rv = *(const float4*)(r + base);
  float qq = qv.x*qv.x + qv.y*qv.y + qv.z*qv.z + qv.w*qv.w;
  float rr = rv.x*rv.x + rv.y*rv.y + rv.z*rv.z + rv.w*rv.w;
  float qr = qv.x*rv.x + qv.y*rv.y + qv.z*rv.z + qv.w*rv.w;
  #pragma unroll
  for (int m = 1; m < 64; m <<= 1) {   // butterfly: every lane gets the sums
    qq += __shfl_xor(qq, m);
    rr += __shfl_xor(rr, m);
    qr += __shfl_xor(qr, m);
  }
  float iq = 1.0f / sqrtf(qq);
  float ir = 1.0f / sqrtf(rr);
  ushort4 qs = { f2bf(qv.x*iq), f2bf(qv.y*iq), f2bf(qv.z*iq), f2bf(qv.w*iq) };
  ushort4 rs = { f2bf(rv.x*ir), f2bf(rv.y*ir), f2bf(rv.z*ir), f2bf(rv.w*ir) };
  *(ushort4*)(qbf + base) = qs;
  *(ushort4*)(rbf + base) = rs;
  if (lane == 0) {
    pos[row] = qr * iq * ir;   // exact f32 diagonal from raw inputs
    row_sum[row] = 0.0f;
  }
}

// stage one 32-col x 256-K bf16 B tile (16 KB) into LDS, async, swizzled.
// LDS logical layout: byte(col, inner) = col*512 + (inner ^ ((col&7)<<4)).
// global_load_lds writes linearly, so the swizzle is applied to the SOURCE
// address (rule 21: inverse-swz source + swz read).
__device__ __forceinline__ void stage_tile(unsigned short* dst,
                                           const unsigned short* src_base,
                                           int col0, int wid, int lane) {
  const char* gb = (const char*)src_base + (size_t)col0 * 512;
  #pragma unroll
  for (int it = 0; it < 4; ++it) {
    int cb = wid * 256 + it * 64;        // wave-uniform chunk base (16B units)
    int chunk = cb + lane;               // 0..1023
    int cc = chunk >> 5;                 // tile-local col 0..31
    int inner = (chunk & 31) << 4;       // byte offset within 512B row
    int off = cc * 512 + (inner ^ ((cc & 7) << 4));
    __builtin_amdgcn_global_load_lds(
        (const __attribute__((address_space(1))) void*)(gb + off),
        (__attribute__((address_space(3))) void*)((char*)dst + cb * 16),
        16, 0, 0);
  }
}

// one 256x32 tile: 8 K-steps, A from PINNED registers (4 frags), B from LDS
// (2 b128 reads per K-step), 8 MFMA per K-step -> 4 MFMA per ds_read_b128.
__device__ __forceinline__ void compute_tile(
    const unsigned short* Bt, const i32x4 (&av)[4][8], float (&rs)[16],
    int g, int c) {
  const char* Bb = (const char*)Bt;
  f32x4 acc[4][2];
  const f32x4 zero = {0.f, 0.f, 0.f, 0.f};
  #pragma unroll
  for (int m = 0; m < 4; ++m) { acc[m][0] = zero; acc[m][1] = zero; }

  #pragma unroll
  for (int ks = 0; ks < 8; ++ks) {
    int kin = ks * 64 + g * 16;
    int c1 = 16 + c;
    bf16x8 bv0 = *(const bf16x8*)(Bb + (size_t)c  * 512 + (kin ^ ((c  & 7) << 4)));
    bf16x8 bv1 = *(const bf16x8*)(Bb + (size_t)c1 * 512 + (kin ^ ((c1 & 7) << 4)));
    #pragma unroll
    for (int m = 0; m < 4; ++m) {
      bf16x8 a = __builtin_bit_cast(bf16x8, av[m][ks]);
      acc[m][0] = __builtin_amdgcn_mfma_f32_16x16x32_bf16(a, bv0, acc[m][0], 0, 0, 0);
      acc[m][1] = __builtin_amdgcn_mfma_f32_16x16x32_bf16(a, bv1, acc[m][1], 0, 0, 0);
    }
  }

  // unit-norm inputs: score = acc. C layout (validated r1):
  // col = nn*16 + c, row = m*16 + g*4 + j
  #pragma unroll
  for (int m = 0; m < 4; ++m)
    #pragma unroll
    for (int j = 0; j < 4; ++j)
      rs[m * 4 + j] += __expf(acc[m][0][j]) + __expf(acc[m][1][j]);
}

__global__ __launch_bounds__(256, 1) void gemm_lse_kernel(
    const unsigned short* __restrict__ qbf, const unsigned short* __restrict__ rbf,
    float* __restrict__ row_sum) {
  __shared__ __attribute__((aligned(16))) unsigned short Bl[2][BCOLS * DDIM]; // 2 x 16 KB

  const int tid  = threadIdx.x;
  const int lane = tid & 63;
  const int wid  = tid >> 6;            // 4 waves, each owns 64 rows
  const int g = lane >> 4, c = lane & 15;
  const int row0  = blockIdx.x * BROWS;
  const int col00 = blockIdx.y * (NTILES * BCOLS);

  // issue stage of tile 0 first; latency hides under the A-register loads
  stage_tile(&Bl[0][0], rbf, col00, wid, lane);

  // A fragments -> registers (4 row-frags x 8 K-slices = 128 VGPR), read once.
  // asm-pin each fragment: the asm def cannot be rematerialized, so the
  // allocator must keep them live instead of re-loading per tile (the R4
  // failure: VGPR_Count=104 < 128 proved av never stayed resident).
  i32x4 av[4][8];
  const char* Ab = (const char*)qbf;
  #pragma unroll
  for (int m = 0; m < 4; ++m) {
    size_t rb = (size_t)(row0 + wid * 64 + m * 16 + c) * 512;
    #pragma unroll
    for (int ks = 0; ks < 8; ++ks) {
      av[m][ks] = *(const i32x4*)(Ab + rb + ks * 64 + g * 16);
      asm volatile("" : "+v"(av[m][ks]));
    }
  }

  float rs[16];
  #pragma unroll
  for (int k = 0; k < 16; ++k) rs[k] = 0.0f;

  __syncthreads();   // tile 0 resident

  // 2-phase pipeline: issue stage(t+1) BEFORE compute(t); the single
  // __syncthreads per tile drains vmcnt AFTER compute so in-flight loads
  // hide under MFMA. Manual x2 unroll keeps buffer indices compile-time.
  for (int t = 0; t < NTILES; t += 2) {
    if (t + 1 < NTILES)
      stage_tile(&Bl[1][0], rbf, col00 + (t + 1) * BCOLS, wid, lane);
    compute_tile(&Bl[0][0], av, rs, g, c);
    __syncthreads();

    if (t + 2 < NTILES)
      stage_tile(&Bl[0][0], rbf, col00 + (t + 2) * BCOLS, wid, lane);
    compute_tile(&Bl[1][0], av, rs, g, c);
    __syncthreads();
  }

  // reduce the 16 column-lanes holding the same row, one atomic per row
  #pragma unroll
  for (int k = 0; k < 16; ++k) {
    float v = rs[k];
    v += __shfl_xor(v, 1);
    v += __shfl_xor(v, 2);
    v += __shfl_xor(v, 4);
    v += __shfl_xor(v, 8);
    if (c == 0) {
      int row = row0 + wid * 64 + (k >> 2) * 16 + g * 4 + (k & 3);
      atomicAdd(&row_sum[row], v);
    }
  }
}

__global__ __launch_bounds__(256) void finalize_kernel(
    const float* __restrict__ row_sum, const float* __restrict__ pos,
    float* __restrict__ out, int n) {
  int t = threadIdx.x;
  float s = 0.f;
  #pragma unroll 4
  for (int i = t; i < n; i += 256) s += __logf(row_sum[i]) - pos[i];
  #pragma unroll
  for (int m = 1; m < 64; m <<= 1) s += __shfl_xor(s, m);
  __shared__ float red[4];
  if ((t & 63) == 0) red[t >> 6] = s;
  __syncthreads();
  if (t == 0) out[0] = red[0] + red[1] + red[2] + red[3];  // -loss = sum(lse - pos)
}

extern "C" void kernel_launch(void* const* d_in, const int* in_sizes, int n_in,
                              void* d_out, int out_size, void* d_ws, size_t ws_size,
                              hipStream_t stream) {
  const float* q = (const float*)d_in[0];
  const float* r = (const float*)d_in[1];
  int n = in_sizes[0] / DDIM;  // 8192

  char* w = (char*)d_ws;
  size_t bfBytes = (size_t)n * DDIM * 2;
  unsigned short* qbf = (unsigned short*)w;
  unsigned short* rbf = (unsigned short*)(w + bfBytes);
  float* pos     = (float*)(w + 2 * bfBytes);
  float* row_sum = pos + n;

  prep_kernel<<<n / 4, 256, 0, stream>>>(q, r, qbf, rbf, pos, row_sum);

  dim3 grid(n / BROWS, n / (NTILES * BCOLS));   // 32 x 32 = 1024 blocks
  gemm_lse_kernel<<<grid, 256, 0, stream>>>(qbf, rbf, row_sum);

  finalize_kernel<<<1, 256, 0, stream>>>(row_sum, pos, (float*)d_out, n);
}

// Round 6
// 52.592 us; speedup vs baseline: 1.1848x; 1.1848x over previous
//
#include <hip/hip_runtime.h>
#include <hip/hip_bf16.h>

#define DDIM   256   // K (feature dim)
#define BROWS  512   // block output rows (8 waves x 64 rows)
#define BCOLS   32   // B tile columns
#define NTILES  16   // B tiles per block -> 512 cols per chunk

typedef __bf16 bf16x8 __attribute__((ext_vector_type(8)));
typedef float  f32x4  __attribute__((ext_vector_type(4)));
typedef int    i32x4  __attribute__((ext_vector_type(4)));

// round-to-nearest-even f32 -> bf16 bits
__device__ __forceinline__ unsigned short f2bf(float f) {
  unsigned int u = __float_as_uint(f);
  return (unsigned short)((u + 0x7fffu + ((u >> 16) & 1u)) >> 16);
}

// ---- prep: one wave per row; writes UNIT-NORM bf16 rows + exact f32 diag ----
__global__ __launch_bounds__(256) void prep_kernel(
    const float* __restrict__ q, const float* __restrict__ r,
    unsigned short* __restrict__ qbf, unsigned short* __restrict__ rbf,
    float* __restrict__ pos, float* __restrict__ row_sum) {
  int lane = threadIdx.x & 63, wave = threadIdx.x >> 6;
  int row = blockIdx.x * 4 + wave;
  size_t base = (size_t)row * DDIM + lane * 4;
  float4 qv = *(const float4*)(q + base);
  float4 rv = *(const float4*)(r + base);
  float qq = qv.x*qv.x + qv.y*qv.y + qv.z*qv.z + qv.w*qv.w;
  float rr = rv.x*rv.x + rv.y*rv.y + rv.z*rv.z + rv.w*rv.w;
  float qr = qv.x*rv.x + qv.y*rv.y + qv.z*rv.z + qv.w*rv.w;
  #pragma unroll
  for (int m = 1; m < 64; m <<= 1) {   // butterfly: every lane gets the sums
    qq += __shfl_xor(qq, m);
    rr += __shfl_xor(rr, m);
    qr += __shfl_xor(qr, m);
  }
  float iq = 1.0f / sqrtf(qq);
  float ir = 1.0f / sqrtf(rr);
  ushort4 qs = { f2bf(qv.x*iq), f2bf(qv.y*iq), f2bf(qv.z*iq), f2bf(qv.w*iq) };
  ushort4 rs = { f2bf(rv.x*ir), f2bf(rv.y*ir), f2bf(rv.z*ir), f2bf(rv.w*ir) };
  *(ushort4*)(qbf + base) = qs;
  *(ushort4*)(rbf + base) = rs;
  if (lane == 0) {
    pos[row] = qr * iq * ir;   // exact f32 diagonal from raw inputs
    row_sum[row] = 0.0f;
  }
}

// stage one 32-col x 256-K bf16 B tile (16 KB) into LDS, async, swizzled.
// LDS layout: byte(col, inner) = col*512 + (inner ^ ((col&7)<<4)).
// global_load_lds writes linearly, so the swizzle is applied to the SOURCE
// address (rule 21). 512 threads -> 2 chunks of 16B each.
__device__ __forceinline__ void stage_tile(unsigned short* dst,
                                           const unsigned short* src_base,
                                           int col0, int wid, int lane) {
  const char* gb = (const char*)src_base + (size_t)col0 * 512;
  #pragma unroll
  for (int it = 0; it < 2; ++it) {
    int cb = wid * 128 + it * 64;        // wave-uniform chunk base (16B units)
    int chunk = cb + lane;               // 0..1023
    int cc = chunk >> 5;                 // tile-local col 0..31
    int inner = (chunk & 31) << 4;       // byte offset within 512B row
    int off = cc * 512 + (inner ^ ((cc & 7) << 4));
    __builtin_amdgcn_global_load_lds(
        (const __attribute__((address_space(1))) void*)(gb + off),
        (__attribute__((address_space(3))) void*)((char*)dst + cb * 16),
        16, 0, 0);
  }
}

// one 512x32 tile: 8 K-steps, A from resident registers (4 frags/wave),
// B from LDS (2 b128 reads/K-step), 8 MFMA per K-step per wave.
__device__ __forceinline__ void compute_tile(
    const unsigned short* Bt, const i32x4 (&av)[4][8], float (&rs)[16],
    int g, int c) {
  const char* Bb = (const char*)Bt;
  f32x4 acc[4][2];
  const f32x4 zero = {0.f, 0.f, 0.f, 0.f};
  #pragma unroll
  for (int m = 0; m < 4; ++m) { acc[m][0] = zero; acc[m][1] = zero; }

  #pragma unroll
  for (int ks = 0; ks < 8; ++ks) {
    int kin = ks * 64 + g * 16;
    int c1 = 16 + c;
    bf16x8 bv0 = *(const bf16x8*)(Bb + (size_t)c  * 512 + (kin ^ ((c  & 7) << 4)));
    bf16x8 bv1 = *(const bf16x8*)(Bb + (size_t)c1 * 512 + (kin ^ ((c1 & 7) << 4)));
    #pragma unroll
    for (int m = 0; m < 4; ++m) {
      bf16x8 a = __builtin_bit_cast(bf16x8, av[m][ks]);
      acc[m][0] = __builtin_amdgcn_mfma_f32_16x16x32_bf16(a, bv0, acc[m][0], 0, 0, 0);
      acc[m][1] = __builtin_amdgcn_mfma_f32_16x16x32_bf16(a, bv1, acc[m][1], 0, 0, 0);
    }
  }

  // unit-norm inputs: score = acc. C layout (validated r1):
  // col = nn*16 + c, row = m*16 + g*4 + j
  #pragma unroll
  for (int m = 0; m < 4; ++m)
    #pragma unroll
    for (int j = 0; j < 4; ++j)
      rs[m * 4 + j] += __expf(acc[m][0][j]) + __expf(acc[m][1][j]);
}

// 512 threads = 8 waves = 2 waves/SIMD at 1 block/CU. launch_bounds(512,2)
// tells the allocator 2 waves/EU -> 256-VGPR budget, enough for av[4][8]
// (128) + acc (32) + rs (16) + staging to stay resident (the R3-R5 failures
// were the allocator capping at 128 and re-loading A from L2 every tile).
__global__ __launch_bounds__(512, 2) void gemm_lse_kernel(
    const unsigned short* __restrict__ qbf, const unsigned short* __restrict__ rbf,
    float* __restrict__ row_sum) {
  __shared__ __attribute__((aligned(16))) unsigned short Bl[2][BCOLS * DDIM]; // 2 x 16 KB

  const int tid  = threadIdx.x;
  const int lane = tid & 63;
  const int wid  = tid >> 6;            // 8 waves, each owns 64 rows
  const int g = lane >> 4, c = lane & 15;
  const int row0  = blockIdx.x * BROWS;
  const int col00 = blockIdx.y * (NTILES * BCOLS);

  // issue stage of tile 0 first; latency hides under the A-register loads
  stage_tile(&Bl[0][0], rbf, col00, wid, lane);

  // A fragments -> registers (4 row-frags x 8 K-slices = 128 VGPR), read once
  i32x4 av[4][8];
  const char* Ab = (const char*)qbf;
  #pragma unroll
  for (int m = 0; m < 4; ++m) {
    size_t rb = (size_t)(row0 + wid * 64 + m * 16 + c) * 512;
    #pragma unroll
    for (int ks = 0; ks < 8; ++ks) {
      av[m][ks] = *(const i32x4*)(Ab + rb + ks * 64 + g * 16);
      asm volatile("" : "+v"(av[m][ks]));   // pin: forbid remat/re-load
    }
  }

  float rs[16];
  #pragma unroll
  for (int k = 0; k < 16; ++k) rs[k] = 0.0f;

  __syncthreads();   // tile 0 resident

  // 2-phase pipeline: issue stage(t+1) BEFORE compute(t). compute(t) is
  // ~2500 CU-cycles of MFMA, far exceeding the ~300-cycle L2 latency of the
  // in-flight stage, so the vmcnt(0) drain inside __syncthreads costs ~0.
  for (int t = 0; t < NTILES; t += 2) {
    if (t + 1 < NTILES)
      stage_tile(&Bl[1][0], rbf, col00 + (t + 1) * BCOLS, wid, lane);
    compute_tile(&Bl[0][0], av, rs, g, c);
    __syncthreads();

    if (t + 2 < NTILES)
      stage_tile(&Bl[0][0], rbf, col00 + (t + 2) * BCOLS, wid, lane);
    compute_tile(&Bl[1][0], av, rs, g, c);
    __syncthreads();
  }

  // reduce the 16 column-lanes holding the same row, one atomic per row
  #pragma unroll
  for (int k = 0; k < 16; ++k) {
    float v = rs[k];
    v += __shfl_xor(v, 1);
    v += __shfl_xor(v, 2);
    v += __shfl_xor(v, 4);
    v += __shfl_xor(v, 8);
    if (c == 0) {
      int row = row0 + wid * 64 + (k >> 2) * 16 + g * 4 + (k & 3);
      atomicAdd(&row_sum[row], v);
    }
  }
}

__global__ __launch_bounds__(256) void finalize_kernel(
    const float* __restrict__ row_sum, const float* __restrict__ pos,
    float* __restrict__ out, int n) {
  int t = threadIdx.x;
  float s = 0.f;
  #pragma unroll 4
  for (int i = t; i < n; i += 256) s += __logf(row_sum[i]) - pos[i];
  #pragma unroll
  for (int m = 1; m < 64; m <<= 1) s += __shfl_xor(s, m);
  __shared__ float red[4];
  if ((t & 63) == 0) red[t >> 6] = s;
  __syncthreads();
  if (t == 0) out[0] = red[0] + red[1] + red[2] + red[3];  // -loss = sum(lse - pos)
}

extern "C" void kernel_launch(void* const* d_in, const int* in_sizes, int n_in,
                              void* d_out, int out_size, void* d_ws, size_t ws_size,
                              hipStream_t stream) {
  const float* q = (const float*)d_in[0];
  const float* r = (const float*)d_in[1];
  int n = in_sizes[0] / DDIM;  // 8192

  char* w = (char*)d_ws;
  size_t bfBytes = (size_t)n * DDIM * 2;
  unsigned short* qbf = (unsigned short*)w;
  unsigned short* rbf = (unsigned short*)(w + bfBytes);
  float* pos     = (float*)(w + 2 * bfBytes);
  float* row_sum = pos + n;

  prep_kernel<<<n / 4, 256, 0, stream>>>(q, r, qbf, rbf, pos, row_sum);

  dim3 grid(n / BROWS, n / (NTILES * BCOLS));   // 16 x 16 = 256 blocks (1/CU)
  gemm_lse_kernel<<<grid, 512, 0, stream>>>(qbf, rbf, row_sum);

  finalize_kernel<<<1, 256, 0, stream>>>(row_sum, pos, (float*)d_out, n);
}